// Round 1
// baseline (1354.014 us; speedup 1.0000x reference)
//
#include <hip/hip_runtime.h>

// ReactantCentreIdentify: per-graph masked mean pool + gated broadcast concat.
// N=400000 nodes, D=300, B=4096 graphs. batch[] is SORTED -> each graph is a
// contiguous node range; one block per graph, binary search for the range.
//
// Traffic: read node_rep once (480 MB), write out once (960 MB). Memory-bound.

constexpr int D      = 300;
constexpr int DV     = D / 4;        // 75 float4 per input row
constexpr int ODV    = 2 * DV;       // 150 float4 per output row
constexpr int NSUB   = 3;            // nodes processed concurrently
constexpr int ACTIVE = DV * NSUB;    // 225 active lanes
constexpr int BLOCK  = 256;
constexpr int NUM_GRAPHS = 4096;     // problem config (num_graphs is a device scalar)

__device__ __forceinline__ int lower_bound_i32(const int* __restrict__ a, int n, int key) {
    int lo = 0, hi = n;
    while (lo < hi) {
        int mid = (lo + hi) >> 1;
        if (a[mid] < key) lo = mid + 1; else hi = mid;
    }
    return lo;
}

__global__ __launch_bounds__(BLOCK)
void fused_pool_concat(const float* __restrict__ node_rep,
                       const int*   __restrict__ batch,
                       const int*   __restrict__ label,
                       float*       __restrict__ out,
                       int n)
{
    const int b = blockIdx.x;

    // Graph b's contiguous node range (uniform across block -> scalar code).
    const int start = lower_bound_i32(batch, n, b);
    const int end   = lower_bound_i32(batch, n, b + 1);

    const int t   = threadIdx.x;
    const int sub = t / DV;        // which node of the trio (0..2); sub==3 for t>=225
    const int j   = t - sub * DV;  // float4 index within the row (0..74)

    const float4* __restrict__ nr4  = reinterpret_cast<const float4*>(node_rep);
    float4*       __restrict__ out4 = reinterpret_cast<float4*>(out);

    float4 acc = make_float4(0.f, 0.f, 0.f, 0.f);
    int cnt = 0;

    if (t < ACTIVE) {
        for (int i0 = start; i0 < end; i0 += NSUB) {
            const int i = i0 + sub;
            if (i < end) {
                const bool cond = (label[i] == -1);       // broadcast within sub-group
                const float4 v = nr4[(size_t)i * DV + j];
                out4[(size_t)i * ODV + j] = v;            // out[i, 0:300] = node_rep[i]
                if (cond) {
                    acc.x += v.x; acc.y += v.y; acc.z += v.z; acc.w += v.w;
                    ++cnt;
                }
            }
        }
    }

    // Reduce the 3 node-subgroups' partial sums (each sub counted the same
    // cnt across its 75 lanes).
    __shared__ float4 s_red[ACTIVE];
    __shared__ float4 s_pool[DV];
    __shared__ int    s_cnt[NSUB];

    if (t < ACTIVE) {
        s_red[t] = acc;
        if (j == 0) s_cnt[sub] = cnt;
    }
    __syncthreads();

    if (t < DV) {
        const float4 s0 = s_red[t];
        const float4 s1 = s_red[t + DV];
        const float4 s2 = s_red[t + 2 * DV];
        const int c = s_cnt[0] + s_cnt[1] + s_cnt[2];
        // Gate: last node of the graph must be a condition node (matches
        // reference segment_max + clip: empty graph -> flag false).
        const bool flag = (end > start) && (label[end - 1] == -1);
        float4 p = make_float4(0.f, 0.f, 0.f, 0.f);
        if (flag) {
            const float inv = 1.0f / (float)((c > 1) ? c : 1);
            p.x = (s0.x + s1.x + s2.x) * inv;
            p.y = (s0.y + s1.y + s2.y) * inv;
            p.z = (s0.z + s1.z + s2.z) * inv;
            p.w = (s0.w + s1.w + s2.w) * inv;
        }
        s_pool[t] = p;
    }
    __syncthreads();

    if (t < ACTIVE) {
        const float4 pool = s_pool[j];
        for (int i0 = start; i0 < end; i0 += NSUB) {
            const int i = i0 + sub;
            if (i < end) {
                out4[(size_t)i * ODV + DV + j] = pool;    // out[i, 300:600] = cond_pool
            }
        }
    }
}

extern "C" void kernel_launch(void* const* d_in, const int* in_sizes, int n_in,
                              void* d_out, int out_size, void* d_ws, size_t ws_size,
                              hipStream_t stream)
{
    const float* node_rep = (const float*)d_in[0];
    const int*   batch    = (const int*)d_in[1];
    const int*   label    = (const int*)d_in[2];
    // d_in[3] = num_graphs lives in device memory; grid dims must be known
    // host-side, and the problem config fixes it at 4096.
    float* out = (float*)d_out;

    const int n = in_sizes[0] / D;   // 400000

    fused_pool_concat<<<NUM_GRAPHS, BLOCK, 0, stream>>>(node_rep, batch, label, out, n);
}